// Round 1
// baseline (331.870 us; speedup 1.0000x reference)
//
#include <hip/hip_runtime.h>
#include <math.h>

#define PHASE_BINS 100
#define EPSF 1e-10f
#define HW 262144           // 512*512
#define BATCH 64
#define BLOCKS_PER_BATCH 32
#define CHUNK (HW / BLOCKS_PER_BATCH)   // 8192 elements per block
#define THREADS 256

__device__ __forceinline__ float wave_reduce_sum(float v) {
    #pragma unroll
    for (int off = 32; off > 0; off >>= 1) v += __shfl_down(v, off, 64);
    return v;
}

// Pass 1: one read of A and B. Per batch accumulate:
//   SA = sum |A|, SB = sum |B|, T = sum |A|*(ln|A| - ln|B|)
// and 100-bin phase histograms of angle(A), angle(B).
__global__ __launch_bounds__(THREADS) void pass1_kernel(
    const float* __restrict__ A, const float* __restrict__ B,
    float* __restrict__ SA, float* __restrict__ SB, float* __restrict__ Tacc,
    unsigned int* __restrict__ histA, unsigned int* __restrict__ histB)
{
    __shared__ unsigned int h[2][4][PHASE_BINS];  // [A/B][wave][bin]
    const int wave = threadIdx.x >> 6;
    const int lane = threadIdx.x & 63;

    for (int i = threadIdx.x; i < 2 * 4 * PHASE_BINS; i += THREADS)
        ((unsigned int*)h)[i] = 0u;
    __syncthreads();

    const int b   = blockIdx.x / BLOCKS_PER_BATCH;
    const int blk = blockIdx.x % BLOCKS_PER_BATCH;
    const size_t base = (size_t)b * (2 * HW);
    const float* Ar = A + base;
    const float* Ai = Ar + HW;
    const float* Br = B + base;
    const float* Bi = Br + HW;
    const int start = blk * CHUNK;

    const float PI_F = 3.14159265358979323846f;
    const float inv_step = (float)PHASE_BINS / (2.0f * PI_F);

    float sA = 0.f, sB = 0.f, t = 0.f;

    for (int i = threadIdx.x * 4; i < CHUNK; i += THREADS * 4) {
        const int idx = start + i;
        float4 ar4 = *(const float4*)(Ar + idx);
        float4 ai4 = *(const float4*)(Ai + idx);
        float4 br4 = *(const float4*)(Br + idx);
        float4 bi4 = *(const float4*)(Bi + idx);
        const float* arp = (const float*)&ar4;
        const float* aip = (const float*)&ai4;
        const float* brp = (const float*)&br4;
        const float* bip = (const float*)&bi4;
        #pragma unroll
        for (int j = 0; j < 4; ++j) {
            float arj = arp[j], aij = aip[j];
            float brj = brp[j], bij = bip[j];
            float aa = sqrtf(arj * arj + aij * aij);
            float bb = sqrtf(brj * brj + bij * bij);
            sA += aa;
            sB += bb;
            if (aa > 0.f)
                t += aa * (__logf(aa) - __logf(fmaxf(bb, 1e-37f)));
            float pa = atan2f(aij, arj);
            float pb = atan2f(bij, brj);
            int ka = (int)floorf((pa + PI_F) * inv_step);
            int kb = (int)floorf((pb + PI_F) * inv_step);
            ka = min(max(ka, 0), PHASE_BINS - 1);
            kb = min(max(kb, 0), PHASE_BINS - 1);
            atomicAdd(&h[0][wave][ka], 1u);
            atomicAdd(&h[1][wave][kb], 1u);
        }
    }

    // reduce the three float sums per wave, one global atomic per wave
    sA = wave_reduce_sum(sA);
    sB = wave_reduce_sum(sB);
    t  = wave_reduce_sum(t);
    if (lane == 0) {
        atomicAdd(&SA[b], sA);
        atomicAdd(&SB[b], sB);
        atomicAdd(&Tacc[b], t);
    }

    __syncthreads();
    // merge the 4 per-wave histograms and push to global
    if (threadIdx.x < PHASE_BINS) {
        int bin = threadIdx.x;
        unsigned v = h[0][0][bin] + h[0][1][bin] + h[0][2][bin] + h[0][3][bin];
        atomicAdd(&histA[b * PHASE_BINS + bin], v);
    } else if (threadIdx.x < 2 * PHASE_BINS) {
        int bin = threadIdx.x - PHASE_BINS;
        unsigned v = h[1][0][bin] + h[1][1][bin] + h[1][2][bin] + h[1][3][bin];
        atomicAdd(&histB[b * PHASE_BINS + bin], v);
    }
}

// Pass 2: tiny finalize. One block; wave w handles batches w, w+4, ...
__global__ __launch_bounds__(256) void pass2_kernel(
    const float* __restrict__ SA, const float* __restrict__ SB,
    const float* __restrict__ T,
    const unsigned int* __restrict__ histA, const unsigned int* __restrict__ histB,
    float* __restrict__ out)
{
    __shared__ float amp_sh[BATCH];
    __shared__ float wave_phase[4];
    const int wave = threadIdx.x >> 6;
    const int lane = threadIdx.x & 63;
    const float PI_F = 3.14159265358979323846f;
    const float step = (2.0f * PI_F) / PHASE_BINS;

    float local_phase = 0.f;
    for (int b = wave; b < BATCH; b += 4) {
        float d_a[2], d_b[2];
        float sum_a = 0.f, sum_b = 0.f;
        #pragma unroll
        for (int r = 0; r < 2; ++r) {
            int bin = lane + r * 64;
            float da = 0.f, db = 0.f;
            if (bin < PHASE_BINS) {
                float e0 = -PI_F + bin * step;
                float e1 = (bin == PHASE_BINS - 1) ? PI_F : (-PI_F + (bin + 1) * step);
                float w = e1 - e0;                       // fp32 edge widths (torch density)
                float denom = (float)HW * w;
                da = (float)histA[b * PHASE_BINS + bin] / denom;
                db = (float)histB[b * PHASE_BINS + bin] / denom;
            }
            d_a[r] = da; d_b[r] = db;
            sum_a += da; sum_b += db;
        }
        #pragma unroll
        for (int off = 32; off > 0; off >>= 1) {
            sum_a += __shfl_xor(sum_a, off, 64);
            sum_b += __shfl_xor(sum_b, off, 64);
        }
        float kl = 0.f;
        #pragma unroll
        for (int r = 0; r < 2; ++r) {
            int bin = lane + r * 64;
            if (bin < PHASE_BINS) {
                float p = d_a[r] / (sum_a + EPSF);
                float q = d_b[r] / (sum_b + EPSF);
                kl += p * logf((p + EPSF) / (q + EPSF));
            }
        }
        #pragma unroll
        for (int off = 32; off > 0; off >>= 1) kl += __shfl_xor(kl, off, 64);
        if (lane == 0) {
            local_phase += kl;
            float sa_raw = SA[b];
            float sa = sa_raw + EPSF;
            float sb = SB[b] + EPSF;
            amp_sh[b] = T[b] / sa + (sa_raw / sa) * logf(sb / sa);
        }
    }
    if (lane == 0) wave_phase[wave] = local_phase;
    __syncthreads();
    float phase_total = wave_phase[0] + wave_phase[1] + wave_phase[2] + wave_phase[3];
    if (threadIdx.x < BATCH)
        out[threadIdx.x] = 0.5f * amp_sh[threadIdx.x] + 0.5f * phase_total;
}

extern "C" void kernel_launch(void* const* d_in, const int* in_sizes, int n_in,
                              void* d_out, int out_size, void* d_ws, size_t ws_size,
                              hipStream_t stream) {
    const float* A = (const float*)d_in[0];
    const float* B = (const float*)d_in[1];
    float* out = (float*)d_out;

    float* SA = (float*)d_ws;
    float* SB = SA + BATCH;
    float* T  = SB + BATCH;
    unsigned int* histA = (unsigned int*)(T + BATCH);
    unsigned int* histB = histA + BATCH * PHASE_BINS;

    size_t zero_bytes = (size_t)(3 * BATCH) * sizeof(float)
                      + (size_t)(2 * BATCH * PHASE_BINS) * sizeof(unsigned int);
    hipMemsetAsync(d_ws, 0, zero_bytes, stream);

    pass1_kernel<<<dim3(BATCH * BLOCKS_PER_BATCH), dim3(THREADS), 0, stream>>>(
        A, B, SA, SB, T, histA, histB);
    pass2_kernel<<<1, 256, 0, stream>>>(SA, SB, T, histA, histB, out);
}